// Round 5
// baseline (14.921 us; speedup 1.0000x reference)
//
#include <hip/hip_runtime.h>
#include <hip/hip_bf16.h>
#include <math.h>

// recon: [B=4, N=64, D=3] f32, gt: [B=4, M=2048, D=3] f32
// P = 2016 tril pairs (i>j); 5 interp pts f in {0,.25,.5,.75,1}; out [B,P].
//
// d_t/2 = w_t + 0.5||K_t||^2,  w_t = K_t.gn + hh = f*Ds' + (1-f)*A
//   gn = -g, hh = 0.5||g||^2 (LDS), Ds' = s.gn+hh (depends on i only),
//   A = e.gn+hh (depends on j only).
// r_t = min_g w_t;  out = 0.4*sum_t r_t + ||e||^2 + e.u + 0.375||u||^2.
//
// Work grouping: 4 pairs per wave (PPW=4) drawn from the SAME row i ->
// one shared Ds' dot and ONE shared t=4 min chain: 48 ops per (4 pairs, g)
// = 12/pair-pt vs 15 generic. Row pairing (a, 64-a): rows a=1..31 pair with
// 64-a giving 64-pair groups; +row 32 alone (32 pairs). 504 chunks of 4 per
// batch; chunks straddling two rows (<5%) take the generic path
// (wave-uniform branch).
#define BATCH 4
#define NPTS 64
#define MGT 2048
#define NPAIR 2016
#define PPW 4
#define THREADS 512
#define WAVES_PER_BLOCK 8
#define CHUNKS_PER_BLOCK WAVES_PER_BLOCK          // 1 chunk per wave
#define BLOCKS_PER_BATCH 63                        // 504 chunks / 8

__global__ __launch_bounds__(THREADS)
void edge_cdis_kernel(const float* __restrict__ recon,
                      const float* __restrict__ gt,
                      float* __restrict__ out) {
    __shared__ float4 gts4[MGT];   // {-gx,-gy,-gz, 0.5||g||^2}, 32 KB

    const int tid  = threadIdx.x;
    const int wib  = tid >> 6;
    const int lane = tid & 63;

    const int b  = blockIdx.x / BLOCKS_PER_BATCH;
    const int cb = (blockIdx.x % BLOCKS_PER_BATCH) * CHUNKS_PER_BLOCK + wib; // 0..503

    // Stage gt[b] -> LDS as (gn, hh)
    const float* __restrict__ gtb = gt + b * (MGT * 3);
    #pragma unroll
    for (int p = tid; p < MGT; p += THREADS) {
        const float gx = gtb[p * 3 + 0];
        const float gy = gtb[p * 3 + 1];
        const float gz = gtb[p * 3 + 2];
        float4 v;
        v.x = -gx; v.y = -gy; v.z = -gz;
        v.w = 0.5f * fmaf(gz, gz, fmaf(gy, gy, gx * gx));
        gts4[p] = v;
    }
    __syncthreads();

    // chunk -> 4 pairs (i_k, j_k)
    int i_[PPW], j_[PPW];
    if (cb >= 496) {                       // row 32: chunks 496..503
        const int base = (cb - 496) * 4;
        #pragma unroll
        for (int k = 0; k < PPW; ++k) { i_[k] = 32; j_[k] = base + k; }
    } else {                               // pairing P: rows a=P+1 and bb=63-P
        const int P = cb >> 4;
        const int o = cb & 15;
        const int a = P + 1;
        const int bb = 63 - P;
        const int slot = o * 4;
        #pragma unroll
        for (int k = 0; k < PPW; ++k) {
            const int sk = slot + k;
            i_[k] = (sk < a) ? a : bb;
            j_[k] = (sk < a) ? sk : (sk - a);
        }
    }
    const bool same_row = (i_[0] == i_[PPW - 1]);

    const float* __restrict__ rb = recon + b * (NPTS * 3);

    float ex[PPW], ey[PPW], ez[PPW];
    float sx[PPW], sy[PPW], sz[PPW];
    float cadd[PPW];
    #pragma unroll
    for (int k = 0; k < PPW; ++k) {
        sx[k] = rb[i_[k] * 3 + 0]; sy[k] = rb[i_[k] * 3 + 1]; sz[k] = rb[i_[k] * 3 + 2];
        ex[k] = rb[j_[k] * 3 + 0]; ey[k] = rb[j_[k] * 3 + 1]; ez[k] = rb[j_[k] * 3 + 2];
        const float ux = sx[k] - ex[k], uy = sy[k] - ey[k], uz = sz[k] - ez[k];
        const float e2 = ex[k]*ex[k] + ey[k]*ey[k] + ez[k]*ez[k];
        const float eu = ex[k]*ux + ey[k]*uy + ez[k]*uz;
        const float c  = ux*ux + uy*uy + uz*uz;
        cadd[k] = e2 + eu + 0.375f * c;
    }

    float r[PPW][5];
    #pragma unroll
    for (int k = 0; k < PPW; ++k)
        #pragma unroll
        for (int t = 0; t < 5; ++t) r[k][t] = 3.4e38f;
    float r4s = 3.4e38f;   // shared t=4 min (same-row path)

    if (same_row) {
        const float Sx = sx[0], Sy = sy[0], Sz = sz[0];
        #pragma unroll 4
        for (int g = lane; g < MGT; g += 64) {
            const float4 gv = gts4[g];
            float Ds = fmaf(Sx, gv.x, gv.w);
            Ds = fmaf(Sy, gv.y, Ds);
            Ds = fmaf(Sz, gv.z, Ds);
            r4s = fminf(r4s, Ds);
            #pragma unroll
            for (int k = 0; k < PPW; ++k) {
                float A = fmaf(ex[k], gv.x, gv.w);
                A = fmaf(ey[k], gv.y, A);
                A = fmaf(ez[k], gv.z, A);
                const float G = Ds - A;
                r[k][0] = fminf(r[k][0], A);
                r[k][1] = fminf(r[k][1], fmaf(0.25f, G, A));
                r[k][2] = fminf(r[k][2], fmaf(0.50f, G, A));
                r[k][3] = fminf(r[k][3], fmaf(0.75f, G, A));
            }
        }
    } else {
        #pragma unroll 4
        for (int g = lane; g < MGT; g += 64) {
            const float4 gv = gts4[g];
            #pragma unroll
            for (int k = 0; k < PPW; ++k) {
                float A = fmaf(ex[k], gv.x, gv.w);
                A = fmaf(ey[k], gv.y, A);
                A = fmaf(ez[k], gv.z, A);
                float Ds = fmaf(sx[k], gv.x, gv.w);
                Ds = fmaf(sy[k], gv.y, Ds);
                Ds = fmaf(sz[k], gv.z, Ds);
                const float G = Ds - A;
                r[k][0] = fminf(r[k][0], A);
                r[k][1] = fminf(r[k][1], fmaf(0.25f, G, A));
                r[k][2] = fminf(r[k][2], fmaf(0.50f, G, A));
                r[k][3] = fminf(r[k][3], fmaf(0.75f, G, A));
                r[k][4] = fminf(r[k][4], Ds);
            }
        }
    }

    // Wave-wide min reductions
    #pragma unroll
    for (int k = 0; k < PPW; ++k)
        #pragma unroll
        for (int t = 0; t < 5; ++t)
            #pragma unroll
            for (int off = 32; off >= 1; off >>= 1)
                r[k][t] = fminf(r[k][t], __shfl_xor(r[k][t], off, 64));
    #pragma unroll
    for (int off = 32; off >= 1; off >>= 1)
        r4s = fminf(r4s, __shfl_xor(r4s, off, 64));

    if (lane == 0) {
        #pragma unroll
        for (int k = 0; k < PPW; ++k) {
            const float r4 = same_row ? r4s : r[k][4];
            const float sr = r[k][0] + r[k][1] + r[k][2] + r[k][3] + r4;
            const int p = i_[k] * (i_[k] - 1) / 2 + j_[k];
            out[b * NPAIR + p] = 0.4f * sr + cadd[k];
        }
    }
}

extern "C" void kernel_launch(void* const* d_in, const int* in_sizes, int n_in,
                              void* d_out, int out_size, void* d_ws, size_t ws_size,
                              hipStream_t stream) {
    const float* recon = (const float*)d_in[0];
    const float* gt    = (const float*)d_in[1];
    float* out = (float*)d_out;

    const int blocks = BATCH * BLOCKS_PER_BATCH;  // 252
    edge_cdis_kernel<<<blocks, THREADS, 0, stream>>>(recon, gt, out);
}

// Round 6
// 12.670 us; speedup vs baseline: 1.1776x; 1.1776x over previous
//
#include <hip/hip_runtime.h>
#include <hip/hip_bf16.h>
#include <math.h>

// recon: [B=4, N=64, D=3] f32, gt: [B=4, M=2048, D=3] f32
// P = 2016 tril pairs (i>j); 5 interp pts f in {0,.25,.5,.75,1}; out [B,P].
//
// d_t/2 = w_t + const(pair,t),  w_t = (1-f)*A + f*Ds = A + f*(Ds-A)
//   gn = -g, hh = 0.5||g||^2 (LDS);  A = e.gn+hh (j only), Ds = s.gn+hh (i only)
// r_t = min_g w_t;  out = 0.4*sum_t r_t + ||e||^2 + e.u + 0.375||u||^2.
//
// Geometry (R4-proven): 1024 thr x 252 blocks = 4032 waves = 4 waves/SIMD
// (R5 showed 2 waves/SIMD costs ~1.65x in issue efficiency).
// Each wave owns a chunk of 2 CONSECUTIVE pairs (2c, 2c+1): ~97% share row i
// -> shared Ds dot + shared t=4 min chain (26 math ops/iter vs 30);
// straddle chunks (~3%, wave-uniform) take the generic path.
#define BATCH 4
#define NPTS 64
#define MGT 2048
#define NPAIR 2016
#define PPW 2
#define THREADS 1024
#define WAVES_PER_BLOCK 16
#define CHUNKS_PER_BLOCK 16                 // 1 chunk (2 pairs) per wave
#define BLOCKS_PER_BATCH 63                 // 63*16*2 = 2016 pairs

__global__ __launch_bounds__(THREADS)
void edge_cdis_kernel(const float* __restrict__ recon,
                      const float* __restrict__ gt,
                      float* __restrict__ out) {
    __shared__ float4 gts4[MGT];   // {-gx,-gy,-gz, 0.5||g||^2}, 32 KB

    const int tid  = threadIdx.x;
    const int wib  = tid >> 6;
    const int lane = tid & 63;

    const int b  = blockIdx.x / BLOCKS_PER_BATCH;
    const int cb = (blockIdx.x % BLOCKS_PER_BATCH) * CHUNKS_PER_BLOCK + wib; // 0..1007

    // ---- Stage gt[b] -> LDS as (gn, hh) (loads issued first) ----
    const float* __restrict__ gtb = gt + b * (MGT * 3);
    #pragma unroll
    for (int p = tid; p < MGT; p += THREADS) {
        const float gx = gtb[p * 3 + 0];
        const float gy = gtb[p * 3 + 1];
        const float gz = gtb[p * 3 + 2];
        float4 v;
        v.x = -gx; v.y = -gy; v.z = -gz;
        v.w = 0.5f * fmaf(gz, gz, fmaf(gy, gy, gx * gx));
        gts4[p] = v;
    }

    // ---- Setup hoisted BEFORE the barrier (independent of LDS) ----
    const int p0 = 2 * cb;
    int i0 = (int)((1.0f + sqrtf(1.0f + 8.0f * (float)p0)) * 0.5f);
    while (i0 * (i0 - 1) / 2 > p0) --i0;
    while ((i0 + 1) * i0 / 2 <= p0) ++i0;
    const int j0 = p0 - i0 * (i0 - 1) / 2;
    const bool same_row = (j0 + 1 < i0);
    const int i1 = same_row ? i0 : (i0 + 1);
    const int j1 = same_row ? (j0 + 1) : 0;

    const float* __restrict__ rb = recon + b * (NPTS * 3);
    int i_[PPW] = {i0, i1}, j_[PPW] = {j0, j1};
    float ex[PPW], ey[PPW], ez[PPW];
    float sx[PPW], sy[PPW], sz[PPW];
    float cadd[PPW];
    #pragma unroll
    for (int k = 0; k < PPW; ++k) {
        sx[k] = rb[i_[k] * 3 + 0]; sy[k] = rb[i_[k] * 3 + 1]; sz[k] = rb[i_[k] * 3 + 2];
        ex[k] = rb[j_[k] * 3 + 0]; ey[k] = rb[j_[k] * 3 + 1]; ez[k] = rb[j_[k] * 3 + 2];
        const float ux = sx[k] - ex[k], uy = sy[k] - ey[k], uz = sz[k] - ez[k];
        const float e2 = ex[k]*ex[k] + ey[k]*ey[k] + ez[k]*ez[k];
        const float eu = ex[k]*ux + ey[k]*uy + ez[k]*uz;
        const float c  = ux*ux + uy*uy + uz*uz;
        cadd[k] = e2 + eu + 0.375f * c;
    }

    __syncthreads();

    float r[PPW][5];
    #pragma unroll
    for (int k = 0; k < PPW; ++k)
        #pragma unroll
        for (int t = 0; t < 5; ++t) r[k][t] = 3.4e38f;
    float r4s = 3.4e38f;   // shared t=4 min (same-row path)

    if (same_row) {
        const float Sx = sx[0], Sy = sy[0], Sz = sz[0];
        #pragma unroll 8
        for (int g = lane; g < MGT; g += 64) {
            const float4 gv = gts4[g];
            float Ds = fmaf(Sx, gv.x, gv.w);
            Ds = fmaf(Sy, gv.y, Ds);
            Ds = fmaf(Sz, gv.z, Ds);
            r4s = fminf(r4s, Ds);
            #pragma unroll
            for (int k = 0; k < PPW; ++k) {
                float A = fmaf(ex[k], gv.x, gv.w);
                A = fmaf(ey[k], gv.y, A);
                A = fmaf(ez[k], gv.z, A);
                const float G = Ds - A;
                r[k][0] = fminf(r[k][0], A);
                r[k][1] = fminf(r[k][1], fmaf(0.25f, G, A));
                r[k][2] = fminf(r[k][2], fmaf(0.50f, G, A));
                r[k][3] = fminf(r[k][3], fmaf(0.75f, G, A));
            }
        }
    } else {
        #pragma unroll 8
        for (int g = lane; g < MGT; g += 64) {
            const float4 gv = gts4[g];
            #pragma unroll
            for (int k = 0; k < PPW; ++k) {
                float A = fmaf(ex[k], gv.x, gv.w);
                A = fmaf(ey[k], gv.y, A);
                A = fmaf(ez[k], gv.z, A);
                float Ds = fmaf(sx[k], gv.x, gv.w);
                Ds = fmaf(sy[k], gv.y, Ds);
                Ds = fmaf(sz[k], gv.z, Ds);
                const float G = Ds - A;
                r[k][0] = fminf(r[k][0], A);
                r[k][1] = fminf(r[k][1], fmaf(0.25f, G, A));
                r[k][2] = fminf(r[k][2], fmaf(0.50f, G, A));
                r[k][3] = fminf(r[k][3], fmaf(0.75f, G, A));
                r[k][4] = fminf(r[k][4], Ds);
            }
        }
    }

    // ---- Wave-wide min reductions ----
    #pragma unroll
    for (int k = 0; k < PPW; ++k)
        #pragma unroll
        for (int t = 0; t < 4; ++t)
            #pragma unroll
            for (int off = 32; off >= 1; off >>= 1)
                r[k][t] = fminf(r[k][t], __shfl_xor(r[k][t], off, 64));
    if (same_row) {
        #pragma unroll
        for (int off = 32; off >= 1; off >>= 1)
            r4s = fminf(r4s, __shfl_xor(r4s, off, 64));
    } else {
        #pragma unroll
        for (int k = 0; k < PPW; ++k)
            #pragma unroll
            for (int off = 32; off >= 1; off >>= 1)
                r[k][4] = fminf(r[k][4], __shfl_xor(r[k][4], off, 64));
    }

    if (lane == 0) {
        #pragma unroll
        for (int k = 0; k < PPW; ++k) {
            const float r4 = same_row ? r4s : r[k][4];
            const float sr = r[k][0] + r[k][1] + r[k][2] + r[k][3] + r4;
            out[b * NPAIR + p0 + k] = 0.4f * sr + cadd[k];
        }
    }
}

extern "C" void kernel_launch(void* const* d_in, const int* in_sizes, int n_in,
                              void* d_out, int out_size, void* d_ws, size_t ws_size,
                              hipStream_t stream) {
    const float* recon = (const float*)d_in[0];
    const float* gt    = (const float*)d_in[1];
    float* out = (float*)d_out;

    const int blocks = BATCH * BLOCKS_PER_BATCH;  // 252
    edge_cdis_kernel<<<blocks, THREADS, 0, stream>>>(recon, gt, out);
}